// Round 1
// baseline (48.847 us; speedup 1.0000x reference)
//
#include <hip/hip_runtime.h>
#include <hip/hip_bf16.h>
#include <math.h>

#define NB 4
#define MA 256
#define NFS 128
#define KSEL 8
#define HID 256
#define NOUT 32
#define RCUT 5.0f
#define PI_F 3.14159265358979323846f

// Kernel A: per-row a1 = h.Wa[:128], a2 = h.Wa[128:]; copy z (as float) and r to out.
__global__ void precompute_kernel(const int* __restrict__ z,
                                  const float* __restrict__ r,
                                  const float* __restrict__ h,
                                  const float* __restrict__ Wa,
                                  float* __restrict__ out,
                                  float* __restrict__ a1,
                                  float* __restrict__ a2) {
  const int row = blockIdx.x;   // n*MA + i, 0..1023
  const int t = threadIdx.x;    // 0..63
  const float h0 = h[row * NFS + t];
  const float h1 = h[row * NFS + t + 64];
  float p1 = h0 * Wa[t]       + h1 * Wa[t + 64];
  float p2 = h0 * Wa[NFS + t] + h1 * Wa[NFS + t + 64];
#pragma unroll
  for (int off = 32; off > 0; off >>= 1) {
    p1 += __shfl_down(p1, off);
    p2 += __shfl_down(p2, off);
  }
  if (t == 0) { a1[row] = p1; a2[row] = p2; }
  if (t < 3) out[NB * MA + row * 3 + t] = r[row * 3 + t];
  if (t == 0) out[row] = (float)z[row];
}

// Kernel B: one block per (n,i) row. Pair stage -> denom -> top-8 -> dvk -> MLP -> c.
__global__ __launch_bounds__(256) void main_kernel(
    const int* __restrict__ z, const float* __restrict__ r,
    const float* __restrict__ h,
    const float* __restrict__ a1g, const float* __restrict__ a2g,
    const float* __restrict__ ba,
    const float* __restrict__ Wp1, const float* __restrict__ bp1,
    const float* __restrict__ Wp2, const float* __restrict__ bp2,
    float* __restrict__ out) {
  const int row = blockIdx.x;   // n*MA + i
  const int n = row >> 8;
  const int i = row & 255;
  const int tid = threadIdx.x;
  const int lane = tid & 63;
  const int wave = tid >> 6;

  __shared__ float gsh[MA];
  __shared__ __align__(16) float u_sh[KSEL][2 * NFS];
  __shared__ __align__(16) float hid_sh[KSEL][HID];
  __shared__ float att_sh[KSEL];
  __shared__ int   idx_sh[KSEL];
  __shared__ float dvk_sh[KSEL][3];
  __shared__ float wred_v[4];
  __shared__ int   wred_i[4];
  __shared__ float denom_sh;

  // ---- phase A: g for all j (this thread's j = tid) ----
  const float rix = r[row * 3 + 0], riy = r[row * 3 + 1], riz = r[row * 3 + 2];
  {
    const int jg = n * MA + tid;
    const float dx = r[jg * 3 + 0] - rix;
    const float dy = r[jg * 3 + 1] - riy;
    const float dz = r[jg * 3 + 2] - riz;
    const float d = sqrtf(dx * dx + dy * dy + dz * dz);
    const int mi = (z[row] > -1) ? 1 : 0;
    const int mj = (z[jg] > -1) ? 1 : 0;
    const int mask = max(mi * mj - ((tid == i) ? 1 : 0), 0);
    float g = 0.0f;
    if (mask) {
      const float cf = 0.5f * (cosf(PI_F * fminf(d, RCUT) / RCUT) + 1.0f);
      g = expf(a1g[row] + cf * a2g[jg] + ba[0]);
    }
    gsh[tid] = g;
  }
  __syncthreads();

  // ---- denom = clip(sum g, 1e-8) ----
  {
    float s = gsh[tid];
#pragma unroll
    for (int off = 32; off > 0; off >>= 1) s += __shfl_down(s, off);
    if (lane == 0) wred_v[wave] = s;
  }
  __syncthreads();
  if (tid == 0) denom_sh = fmaxf(wred_v[0] + wred_v[1] + wred_v[2] + wred_v[3], 1e-8f);
  __syncthreads();

  // ---- top-8 (value desc, smaller index on ties — matches lax.top_k) ----
  for (int k = 0; k < KSEL; k++) {
    float bv = gsh[tid];
    int bi = tid;
#pragma unroll
    for (int off = 32; off > 0; off >>= 1) {
      const float ov = __shfl_down(bv, off);
      const int oi = __shfl_down(bi, off);
      if (ov > bv || (ov == bv && oi < bi)) { bv = ov; bi = oi; }
    }
    if (lane == 0) { wred_v[wave] = bv; wred_i[wave] = bi; }
    __syncthreads();
    if (tid == 0) {
      float Bv = wred_v[0]; int Bi = wred_i[0];
#pragma unroll
      for (int w = 1; w < 4; w++) {
        if (wred_v[w] > Bv || (wred_v[w] == Bv && wred_i[w] < Bi)) { Bv = wred_v[w]; Bi = wred_i[w]; }
      }
      idx_sh[k] = Bi;
      att_sh[k] = Bv / denom_sh;
      gsh[Bi] = -1.0f;   // all real g >= 0
    }
    __syncthreads();
  }

  // ---- dvk = normalize(r[idx] - r_i), clip(norm, 1e-4) ----
  if (tid < KSEL) {
    const int jg = n * MA + idx_sh[tid];
    const float dx = r[jg * 3 + 0] - rix;
    const float dy = r[jg * 3 + 1] - riy;
    const float dz = r[jg * 3 + 2] - riz;
    const float nrm = fmaxf(sqrtf(dx * dx + dy * dy + dz * dz), 1e-4f);
    dvk_sh[tid][0] = dx / nrm;
    dvk_sh[tid][1] = dy / nrm;
    dvk_sh[tid][2] = dz / nrm;
  }
  __syncthreads();

  // ---- u[k][f] = att_k * (f<128 ? h_i[f] : h_nb[f-128]) ----
#pragma unroll
  for (int k = 0; k < KSEL; k++) {
    const float a = att_sh[k];
    const int jj = idx_sh[k];
    const float hv = (tid < NFS) ? h[row * NFS + tid]
                                 : h[(n * MA + jj) * NFS + (tid - NFS)];
    u_sh[k][tid] = a * hv;
  }
  __syncthreads();

  // ---- hidden layer: thread owns column `tid` of Wp1; acc over 8 k ----
  {
    float acc[KSEL];
    const float b = bp1[tid];
#pragma unroll
    for (int k = 0; k < KSEL; k++) acc[k] = b;
    for (int f4 = 0; f4 < (2 * NFS) / 4; ++f4) {
      const float w0 = Wp1[(4 * f4 + 0) * HID + tid];
      const float w1 = Wp1[(4 * f4 + 1) * HID + tid];
      const float w2 = Wp1[(4 * f4 + 2) * HID + tid];
      const float w3 = Wp1[(4 * f4 + 3) * HID + tid];
#pragma unroll
      for (int k = 0; k < KSEL; k++) {
        const float4 uu = *(const float4*)&u_sh[k][4 * f4];
        acc[k] = fmaf(uu.x, w0, fmaf(uu.y, w1, fmaf(uu.z, w2, fmaf(uu.w, w3, acc[k]))));
      }
    }
#pragma unroll
    for (int k = 0; k < KSEL; k++) {
      const float x = acc[k];
      hid_sh[k][tid] = x / (1.0f + expf(-x));   // silu
    }
  }
  __syncthreads();

  // ---- layer 2 + scale by dvk, write c ----
  {
    const int k2 = tid >> 5;
    const int o = tid & 31;
    float acc = bp2[o];
    for (int hh = 0; hh < HID; hh += 4) {
      const float4 hv = *(const float4*)&hid_sh[k2][hh];
      acc = fmaf(hv.x, Wp2[(hh + 0) * NOUT + o], acc);
      acc = fmaf(hv.y, Wp2[(hh + 1) * NOUT + o], acc);
      acc = fmaf(hv.z, Wp2[(hh + 2) * NOUT + o], acc);
      acc = fmaf(hv.w, Wp2[(hh + 3) * NOUT + o], acc);
    }
    float* cb = out + NB * MA + NB * MA * 3 + ((size_t)row * KSEL + k2) * (NOUT * 3) + o * 3;
    cb[0] = acc * dvk_sh[k2][0];
    cb[1] = acc * dvk_sh[k2][1];
    cb[2] = acc * dvk_sh[k2][2];
  }
}

extern "C" void kernel_launch(void* const* d_in, const int* in_sizes, int n_in,
                              void* d_out, int out_size, void* d_ws, size_t ws_size,
                              hipStream_t stream) {
  const int*   z   = (const int*)d_in[0];
  const float* r   = (const float*)d_in[1];
  const float* h   = (const float*)d_in[2];
  const float* Wa  = (const float*)d_in[3];
  const float* ba  = (const float*)d_in[4];
  const float* Wp1 = (const float*)d_in[5];
  const float* bp1 = (const float*)d_in[6];
  const float* Wp2 = (const float*)d_in[7];
  const float* bp2 = (const float*)d_in[8];
  float* out = (float*)d_out;
  float* a1 = (float*)d_ws;
  float* a2 = a1 + NB * MA;

  precompute_kernel<<<NB * MA, 64, 0, stream>>>(z, r, h, Wa, out, a1, a2);
  main_kernel<<<NB * MA, 256, 0, stream>>>(z, r, h, a1, a2, ba, Wp1, bp1, Wp2, bp2, out);
}

// Round 2
// 31.593 us; speedup vs baseline: 1.5461x; 1.5461x over previous
//
#include <hip/hip_runtime.h>
#include <hip/hip_bf16.h>
#include <math.h>

#define NB 4
#define MA 256
#define NFS 128
#define KSEL 8
#define HID 256
#define NOUT 32
#define RCUT 5.0f
#define PI_F 3.14159265358979323846f

// Kernel 1: per-row scalars a1 = h.Wa[:128], a2 = h.Wa[128:],
//           P = h @ Wp1[:128,:], Q = h @ Wp1[128:,:], plus z/r copy to out.
// Grid: 512 blocks, each handles 2 consecutive rows (shares the Wp1 read).
__global__ __launch_bounds__(256) void prep_kernel(
    const int* __restrict__ z, const float* __restrict__ r,
    const float* __restrict__ h, const float* __restrict__ Wa,
    const float* __restrict__ Wp1,
    float* __restrict__ out,
    float* __restrict__ a1, float* __restrict__ a2,
    float* __restrict__ P, float* __restrict__ Q) {
  const int b = blockIdx.x;        // rows 2b, 2b+1
  const int t = threadIdx.x;       // 0..255
  const int r0 = 2 * b;
  __shared__ float hsh[2][NFS];

  ((float*)hsh)[t] = h[b * 2 * NFS + t];   // rows 2b,2b+1 are contiguous
  __syncthreads();

  const int wave = t >> 6, lane = t & 63;
  if (wave < 2) {
    // a1/a2 for row r0+wave
    const float h0 = hsh[wave][lane], h1 = hsh[wave][lane + 64];
    float p1 = h0 * Wa[lane]       + h1 * Wa[lane + 64];
    float p2 = h0 * Wa[NFS + lane] + h1 * Wa[NFS + lane + 64];
#pragma unroll
    for (int off = 32; off > 0; off >>= 1) {
      p1 += __shfl_down(p1, off);
      p2 += __shfl_down(p2, off);
    }
    if (lane == 0) { a1[r0 + wave] = p1; a2[r0 + wave] = p2; }
  } else if (wave == 2) {
    if (lane < 2) out[r0 + lane] = (float)z[r0 + lane];
    if (lane < 6) out[NB * MA + r0 * 3 + lane] = r[r0 * 3 + lane];
  }

  // P,Q for both rows; thread owns column t.
  float accP0 = 0.f, accP1 = 0.f, accQ0 = 0.f, accQ1 = 0.f;
  for (int f4 = 0; f4 < NFS / 4; ++f4) {
    const float4 hA = *(const float4*)&hsh[0][4 * f4];
    const float4 hB = *(const float4*)&hsh[1][4 * f4];
    const float wt0 = Wp1[(4 * f4 + 0) * HID + t];
    const float wt1 = Wp1[(4 * f4 + 1) * HID + t];
    const float wt2 = Wp1[(4 * f4 + 2) * HID + t];
    const float wt3 = Wp1[(4 * f4 + 3) * HID + t];
    const float wb0 = Wp1[(NFS + 4 * f4 + 0) * HID + t];
    const float wb1 = Wp1[(NFS + 4 * f4 + 1) * HID + t];
    const float wb2 = Wp1[(NFS + 4 * f4 + 2) * HID + t];
    const float wb3 = Wp1[(NFS + 4 * f4 + 3) * HID + t];
    accP0 = fmaf(hA.x, wt0, fmaf(hA.y, wt1, fmaf(hA.z, wt2, fmaf(hA.w, wt3, accP0))));
    accP1 = fmaf(hB.x, wt0, fmaf(hB.y, wt1, fmaf(hB.z, wt2, fmaf(hB.w, wt3, accP1))));
    accQ0 = fmaf(hA.x, wb0, fmaf(hA.y, wb1, fmaf(hA.z, wb2, fmaf(hA.w, wb3, accQ0))));
    accQ1 = fmaf(hB.x, wb0, fmaf(hB.y, wb1, fmaf(hB.z, wb2, fmaf(hB.w, wb3, accQ1))));
  }
  P[(size_t)r0 * HID + t] = accP0;
  P[(size_t)(r0 + 1) * HID + t] = accP1;
  Q[(size_t)r0 * HID + t] = accQ0;
  Q[(size_t)(r0 + 1) * HID + t] = accQ1;
}

// Kernel 2: one block per (n,i) row. g -> denom -> top-8 -> dvk -> hidden (gather) -> layer2.
__global__ __launch_bounds__(256) void main_kernel(
    const int* __restrict__ z, const float* __restrict__ r,
    const float* __restrict__ a1g, const float* __restrict__ a2g,
    const float* __restrict__ ba,
    const float* __restrict__ Pg, const float* __restrict__ Qg,
    const float* __restrict__ bp1,
    const float* __restrict__ Wp2, const float* __restrict__ bp2,
    float* __restrict__ out) {
  const int row = blockIdx.x;   // n*MA + i
  const int n = row >> 8;
  const int i = row & 255;
  const int tid = threadIdx.x;
  const int lane = tid & 63;
  const int wave = tid >> 6;

  __shared__ float gsh[MA];
  __shared__ __align__(16) float hid_sh[KSEL][HID];
  __shared__ float att_sh[KSEL];
  __shared__ int   idx_sh[KSEL];
  __shared__ float dvk_sh[KSEL][3];
  __shared__ float wred_v[4];
  __shared__ int   wred_i[4];
  __shared__ float denom_sh;

  // ---- phase A: g for all j (this thread's j = tid) ----
  const float rix = r[row * 3 + 0], riy = r[row * 3 + 1], riz = r[row * 3 + 2];
  {
    const int jg = n * MA + tid;
    const float dx = r[jg * 3 + 0] - rix;
    const float dy = r[jg * 3 + 1] - riy;
    const float dz = r[jg * 3 + 2] - riz;
    const float d = sqrtf(dx * dx + dy * dy + dz * dz);
    const int mi = (z[row] > -1) ? 1 : 0;
    const int mj = (z[jg] > -1) ? 1 : 0;
    const int mask = max(mi * mj - ((tid == i) ? 1 : 0), 0);
    float g = 0.0f;
    if (mask) {
      const float cf = 0.5f * (cosf(PI_F * fminf(d, RCUT) / RCUT) + 1.0f);
      g = expf(a1g[row] + cf * a2g[jg] + ba[0]);
    }
    gsh[tid] = g;
  }
  __syncthreads();

  // ---- denom ----
  {
    float s = gsh[tid];
#pragma unroll
    for (int off = 32; off > 0; off >>= 1) s += __shfl_down(s, off);
    if (lane == 0) wred_v[wave] = s;
  }
  __syncthreads();
  if (tid == 0) denom_sh = fmaxf(wred_v[0] + wred_v[1] + wred_v[2] + wred_v[3], 1e-8f);
  __syncthreads();

  // ---- top-8 (value desc, smaller index on ties) ----
  for (int k = 0; k < KSEL; k++) {
    float bv = gsh[tid];
    int bi = tid;
#pragma unroll
    for (int off = 32; off > 0; off >>= 1) {
      const float ov = __shfl_down(bv, off);
      const int oi = __shfl_down(bi, off);
      if (ov > bv || (ov == bv && oi < bi)) { bv = ov; bi = oi; }
    }
    if (lane == 0) { wred_v[wave] = bv; wred_i[wave] = bi; }
    __syncthreads();
    if (tid == 0) {
      float Bv = wred_v[0]; int Bi = wred_i[0];
#pragma unroll
      for (int w = 1; w < 4; w++) {
        if (wred_v[w] > Bv || (wred_v[w] == Bv && wred_i[w] < Bi)) { Bv = wred_v[w]; Bi = wred_i[w]; }
      }
      idx_sh[k] = Bi;
      att_sh[k] = Bv / denom_sh;
      gsh[Bi] = -1.0f;
    }
    __syncthreads();
  }

  // ---- dvk ----
  if (tid < KSEL) {
    const int jg = n * MA + idx_sh[tid];
    const float dx = r[jg * 3 + 0] - rix;
    const float dy = r[jg * 3 + 1] - riy;
    const float dz = r[jg * 3 + 2] - riz;
    const float nrm = fmaxf(sqrtf(dx * dx + dy * dy + dz * dz), 1e-4f);
    dvk_sh[tid][0] = dx / nrm;
    dvk_sh[tid][1] = dy / nrm;
    dvk_sh[tid][2] = dz / nrm;
  }
  __syncthreads();

  // ---- hidden layer via factored GEMM: hid[k][t] = silu(att_k*(P[i][t]+Q[jk][t]) + bp1[t]) ----
  {
    const float pi = Pg[(size_t)row * HID + tid];
    const float bb = bp1[tid];
#pragma unroll
    for (int k = 0; k < KSEL; k++) {
      const float q = Qg[(size_t)(n * MA + idx_sh[k]) * HID + tid];
      const float x = att_sh[k] * (pi + q) + bb;
      hid_sh[k][tid] = x / (1.0f + expf(-x));
    }
  }
  __syncthreads();

  // ---- layer 2 + scale by dvk ----
  {
    const int k2 = tid >> 5;
    const int o = tid & 31;
    float acc = bp2[o];
    for (int hh = 0; hh < HID; hh += 4) {
      const float4 hv = *(const float4*)&hid_sh[k2][hh];
      acc = fmaf(hv.x, Wp2[(hh + 0) * NOUT + o], acc);
      acc = fmaf(hv.y, Wp2[(hh + 1) * NOUT + o], acc);
      acc = fmaf(hv.z, Wp2[(hh + 2) * NOUT + o], acc);
      acc = fmaf(hv.w, Wp2[(hh + 3) * NOUT + o], acc);
    }
    float* cb = out + NB * MA + NB * MA * 3 + ((size_t)row * KSEL + k2) * (NOUT * 3) + o * 3;
    cb[0] = acc * dvk_sh[k2][0];
    cb[1] = acc * dvk_sh[k2][1];
    cb[2] = acc * dvk_sh[k2][2];
  }
}

extern "C" void kernel_launch(void* const* d_in, const int* in_sizes, int n_in,
                              void* d_out, int out_size, void* d_ws, size_t ws_size,
                              hipStream_t stream) {
  const int*   z   = (const int*)d_in[0];
  const float* r   = (const float*)d_in[1];
  const float* h   = (const float*)d_in[2];
  const float* Wa  = (const float*)d_in[3];
  const float* ba  = (const float*)d_in[4];
  const float* Wp1 = (const float*)d_in[5];
  const float* bp1 = (const float*)d_in[6];
  const float* Wp2 = (const float*)d_in[7];
  const float* bp2 = (const float*)d_in[8];
  float* out = (float*)d_out;

  float* a1 = (float*)d_ws;                 // 1024
  float* a2 = a1 + NB * MA;                 // 1024
  float* P  = a2 + NB * MA;                 // 1024*256
  float* Q  = P + (size_t)NB * MA * HID;    // 1024*256  (total ~2.1 MB in ws)

  prep_kernel<<<NB * MA / 2, 256, 0, stream>>>(z, r, h, Wa, Wp1, out, a1, a2, P, Q);
  main_kernel<<<NB * MA, 256, 0, stream>>>(z, r, a1, a2, ba, P, Q, bp1, Wp2, bp2, out);
}

// Round 3
// 28.913 us; speedup vs baseline: 1.6895x; 1.0927x over previous
//
#include <hip/hip_runtime.h>
#include <hip/hip_bf16.h>
#include <math.h>

#define NB 4
#define MA 256
#define NFS 128
#define KSEL 8
#define HID 256
#define NOUT 32
#define RCUT 5.0f
#define PI_F 3.14159265358979323846f

// Kernel 1: 256 blocks x 4 rows. a1/a2 scalars, P = h@Wp1[:128], Q = h@Wp1[128:], z/r copy.
__global__ __launch_bounds__(256) void prep_kernel(
    const int* __restrict__ z, const float* __restrict__ r,
    const float* __restrict__ h, const float* __restrict__ Wa,
    const float* __restrict__ Wp1,
    float* __restrict__ out,
    float* __restrict__ a1, float* __restrict__ a2,
    float* __restrict__ P, float* __restrict__ Q) {
  const int b = blockIdx.x;        // rows 4b..4b+3
  const int t = threadIdx.x;       // 0..255
  const int r0 = 4 * b;
  const int wave = t >> 6, lane = t & 63;
  __shared__ __align__(16) float hsh[4][NFS];

  // load 4 rows of h (contiguous 512 floats) as float2
  ((float2*)hsh)[t] = ((const float2*)(h + (size_t)r0 * NFS))[t];
  __syncthreads();

  // a1/a2: wave w handles row r0+w
  {
    const float h0 = hsh[wave][lane], h1 = hsh[wave][lane + 64];
    float p1 = h0 * Wa[lane]       + h1 * Wa[lane + 64];
    float p2 = h0 * Wa[NFS + lane] + h1 * Wa[NFS + lane + 64];
#pragma unroll
    for (int off = 32; off > 0; off >>= 1) {
      p1 += __shfl_down(p1, off);
      p2 += __shfl_down(p2, off);
    }
    if (lane == 0) { a1[r0 + wave] = p1; a2[r0 + wave] = p2; }
  }
  // z/r copy for these 4 rows
  if (t < 4)  out[r0 + t] = (float)z[r0 + t];
  if (t < 12) out[NB * MA + r0 * 3 + t] = r[r0 * 3 + t];

  // P,Q for 4 rows; thread owns column t of Wp1.
  float aP0 = 0.f, aP1 = 0.f, aP2 = 0.f, aP3 = 0.f;
  float aQ0 = 0.f, aQ1 = 0.f, aQ2 = 0.f, aQ3 = 0.f;
#pragma unroll 2
  for (int f4 = 0; f4 < NFS / 4; ++f4) {
    const float wt0 = Wp1[(4 * f4 + 0) * HID + t];
    const float wt1 = Wp1[(4 * f4 + 1) * HID + t];
    const float wt2 = Wp1[(4 * f4 + 2) * HID + t];
    const float wt3 = Wp1[(4 * f4 + 3) * HID + t];
    const float wb0 = Wp1[(NFS + 4 * f4 + 0) * HID + t];
    const float wb1 = Wp1[(NFS + 4 * f4 + 1) * HID + t];
    const float wb2 = Wp1[(NFS + 4 * f4 + 2) * HID + t];
    const float wb3 = Wp1[(NFS + 4 * f4 + 3) * HID + t];
    const float4 h0 = *(const float4*)&hsh[0][4 * f4];
    const float4 h1 = *(const float4*)&hsh[1][4 * f4];
    const float4 h2 = *(const float4*)&hsh[2][4 * f4];
    const float4 h3 = *(const float4*)&hsh[3][4 * f4];
    aP0 = fmaf(h0.x, wt0, fmaf(h0.y, wt1, fmaf(h0.z, wt2, fmaf(h0.w, wt3, aP0))));
    aP1 = fmaf(h1.x, wt0, fmaf(h1.y, wt1, fmaf(h1.z, wt2, fmaf(h1.w, wt3, aP1))));
    aP2 = fmaf(h2.x, wt0, fmaf(h2.y, wt1, fmaf(h2.z, wt2, fmaf(h2.w, wt3, aP2))));
    aP3 = fmaf(h3.x, wt0, fmaf(h3.y, wt1, fmaf(h3.z, wt2, fmaf(h3.w, wt3, aP3))));
    aQ0 = fmaf(h0.x, wb0, fmaf(h0.y, wb1, fmaf(h0.z, wb2, fmaf(h0.w, wb3, aQ0))));
    aQ1 = fmaf(h1.x, wb0, fmaf(h1.y, wb1, fmaf(h1.z, wb2, fmaf(h1.w, wb3, aQ1))));
    aQ2 = fmaf(h2.x, wb0, fmaf(h2.y, wb1, fmaf(h2.z, wb2, fmaf(h2.w, wb3, aQ2))));
    aQ3 = fmaf(h3.x, wb0, fmaf(h3.y, wb1, fmaf(h3.z, wb2, fmaf(h3.w, wb3, aQ3))));
  }
  P[(size_t)(r0 + 0) * HID + t] = aP0;
  P[(size_t)(r0 + 1) * HID + t] = aP1;
  P[(size_t)(r0 + 2) * HID + t] = aP2;
  P[(size_t)(r0 + 3) * HID + t] = aP3;
  Q[(size_t)(r0 + 0) * HID + t] = aQ0;
  Q[(size_t)(r0 + 1) * HID + t] = aQ1;
  Q[(size_t)(r0 + 2) * HID + t] = aQ2;
  Q[(size_t)(r0 + 3) * HID + t] = aQ3;
}

// Kernel 2: one block per (n,i). g -> wave0 denom+top8 -> dvk/hidden -> layer2.
__global__ __launch_bounds__(256) void main_kernel(
    const int* __restrict__ z, const float* __restrict__ r,
    const float* __restrict__ a1g, const float* __restrict__ a2g,
    const float* __restrict__ ba,
    const float* __restrict__ Pg, const float* __restrict__ Qg,
    const float* __restrict__ bp1,
    const float* __restrict__ Wp2, const float* __restrict__ bp2,
    float* __restrict__ out) {
  const int row = blockIdx.x;   // n*MA + i
  const int n = row >> 8;
  const int i = row & 255;
  const int tid = threadIdx.x;
  const int lane = tid & 63;
  const int wave = tid >> 6;

  __shared__ float gsh[MA];
  __shared__ __align__(16) float hid_sh[KSEL][HID];
  __shared__ float att_sh[KSEL];
  __shared__ int   idx_sh[KSEL];
  __shared__ float dvk_sh[KSEL][3];

  // ---- g for all j (this thread's j = tid) ----
  const float rix = r[row * 3 + 0], riy = r[row * 3 + 1], riz = r[row * 3 + 2];
  {
    const int jg = n * MA + tid;
    const float dx = r[jg * 3 + 0] - rix;
    const float dy = r[jg * 3 + 1] - riy;
    const float dz = r[jg * 3 + 2] - riz;
    const float d = sqrtf(dx * dx + dy * dy + dz * dz);
    const int mi = (z[row] > -1) ? 1 : 0;
    const int mj = (z[jg] > -1) ? 1 : 0;
    const int mask = max(mi * mj - ((tid == i) ? 1 : 0), 0);
    float g = 0.0f;
    if (mask) {
      const float cf = 0.5f * (__cosf(PI_F * fminf(d, RCUT) / RCUT) + 1.0f);
      g = __expf(a1g[row] + cf * a2g[jg] + ba[0]);
    }
    gsh[tid] = g;
  }
  __syncthreads();

  // ---- wave 0: denom + top-8 entirely via shfl (no barriers, no serial section) ----
  if (wave == 0) {
    float v0 = gsh[lane];
    float v1 = gsh[lane + 64];
    float v2 = gsh[lane + 128];
    float v3 = gsh[lane + 192];
    // denom = clip(sum, 1e-8)
    float s = (v0 + v1) + (v2 + v3);
#pragma unroll
    for (int off = 32; off > 0; off >>= 1) s += __shfl_xor(s, off);
    const float rden = 1.0f / fmaxf(s, 1e-8f);
#pragma unroll
    for (int k = 0; k < KSEL; k++) {
      // local argmax of 4 (ascending index order + strict > keeps smallest index on ties)
      float bv = v0; int bi = lane;
      if (v1 > bv) { bv = v1; bi = lane + 64; }
      if (v2 > bv) { bv = v2; bi = lane + 128; }
      if (v3 > bv) { bv = v3; bi = lane + 192; }
      // butterfly all-reduce argmax (lexicographic: value desc, index asc)
#pragma unroll
      for (int off = 32; off > 0; off >>= 1) {
        const float ov = __shfl_xor(bv, off);
        const int oi = __shfl_xor(bi, off);
        if (ov > bv || (ov == bv && oi < bi)) { bv = ov; bi = oi; }
      }
      if (lane == 0) { idx_sh[k] = bi; att_sh[k] = bv * rden; }
      // clear winner (static slot indexing)
      const int slot = bi >> 6, who = bi & 63;
      if (lane == who) {
        if (slot == 0) v0 = -1.0f;
        else if (slot == 1) v1 = -1.0f;
        else if (slot == 2) v2 = -1.0f;
        else v3 = -1.0f;
      }
    }
  }
  __syncthreads();

  // ---- dvk (8 threads) ----
  if (tid < KSEL) {
    const int jg = n * MA + idx_sh[tid];
    const float dx = r[jg * 3 + 0] - rix;
    const float dy = r[jg * 3 + 1] - riy;
    const float dz = r[jg * 3 + 2] - riz;
    const float nrm = fmaxf(sqrtf(dx * dx + dy * dy + dz * dz), 1e-4f);
    dvk_sh[tid][0] = dx / nrm;
    dvk_sh[tid][1] = dy / nrm;
    dvk_sh[tid][2] = dz / nrm;
  }

  // ---- hidden: hid[k][t] = silu(att_k*(P[i][t]+Q[jk][t]) + bp1[t]) ----
  {
    const float pi = Pg[(size_t)row * HID + tid];
    const float bb = bp1[tid];
#pragma unroll
    for (int k = 0; k < KSEL; k++) {
      const float q = Qg[(size_t)(n * MA + idx_sh[k]) * HID + tid];
      const float x = att_sh[k] * (pi + q) + bb;
      hid_sh[k][tid] = x / (1.0f + __expf(-x));
    }
  }
  __syncthreads();

  // ---- layer 2 + scale by dvk ----
  {
    const int k2 = tid >> 5;
    const int o = tid & 31;
    float acc = bp2[o];
    for (int hh = 0; hh < HID; hh += 4) {
      const float4 hv = *(const float4*)&hid_sh[k2][hh];
      acc = fmaf(hv.x, Wp2[(hh + 0) * NOUT + o], acc);
      acc = fmaf(hv.y, Wp2[(hh + 1) * NOUT + o], acc);
      acc = fmaf(hv.z, Wp2[(hh + 2) * NOUT + o], acc);
      acc = fmaf(hv.w, Wp2[(hh + 3) * NOUT + o], acc);
    }
    float* cb = out + NB * MA + NB * MA * 3 + ((size_t)row * KSEL + k2) * (NOUT * 3) + o * 3;
    cb[0] = acc * dvk_sh[k2][0];
    cb[1] = acc * dvk_sh[k2][1];
    cb[2] = acc * dvk_sh[k2][2];
  }
}

extern "C" void kernel_launch(void* const* d_in, const int* in_sizes, int n_in,
                              void* d_out, int out_size, void* d_ws, size_t ws_size,
                              hipStream_t stream) {
  const int*   z   = (const int*)d_in[0];
  const float* r   = (const float*)d_in[1];
  const float* h   = (const float*)d_in[2];
  const float* Wa  = (const float*)d_in[3];
  const float* ba  = (const float*)d_in[4];
  const float* Wp1 = (const float*)d_in[5];
  const float* bp1 = (const float*)d_in[6];
  const float* Wp2 = (const float*)d_in[7];
  const float* bp2 = (const float*)d_in[8];
  float* out = (float*)d_out;

  float* a1 = (float*)d_ws;                 // 1024
  float* a2 = a1 + NB * MA;                 // 1024
  float* P  = a2 + NB * MA;                 // 1024*256
  float* Q  = P + (size_t)NB * MA * HID;    // 1024*256

  prep_kernel<<<NB * MA / 4, 256, 0, stream>>>(z, r, h, Wa, Wp1, out, a1, a2, P, Q);
  main_kernel<<<NB * MA, 256, 0, stream>>>(z, r, a1, a2, ba, P, Q, bp1, Wp2, bp2, out);
}